// Round 7
// baseline (274.859 us; speedup 1.0000x reference)
//
#include <hip/hip_runtime.h>

#define BS    64
#define CIN   128
#define OCH   128
#define HW    56
#define KEXP  8
#define KTOT  1152             // 9 * 128
#define NSTEP 36               // k-steps of 32
#define PLANEC 3364            // 58*58 16B-chunks per (b,quarter,octet) plane
#define WMIX_PS (NSTEP * OCH * 32)   // 147456 elems per sample
#define TPAD  60               // prep_xt LDS row stride (8B-aligned rows, conflict-free gather)

typedef __bf16 bf16x8 __attribute__((ext_vector_type(8)));
typedef __bf16 bf16x4 __attribute__((ext_vector_type(4)));
typedef float  f32x4  __attribute__((ext_vector_type(4)));

__device__ __forceinline__ unsigned f2bf(float f) {
    union { float f; unsigned u; } v; v.f = f;
    unsigned r = v.u + 0x7fffu + ((v.u >> 16) & 1u);   // RNE
    return r >> 16;
}

__device__ __forceinline__ void gl16(const unsigned short* g, unsigned short* l) {
    __builtin_amdgcn_global_load_lds(
        (const __attribute__((address_space(1))) void*)g,
        (__attribute__((address_space(3))) void*)l, 16, 0, 0);
}

// x [64][128][56][56] f32 -> x_t [64][qq=4][oct=4][58][58] chunks of 16 B
// (chunk = 8 channels c = qq*32+oct*8+k, bf16, zero halos).
// Phase 1: float4 loads -> native bf16 casts (v_cvt_pk_bf16_f32) -> one 8B
// LDS write (TPAD=60 keeps rows 8B-aligned). Phase 2: 8-channel gather per
// chunk (conflict-free: col-ranges per wave-read are disjoint across octets),
// coalesced uint4 stores.
__global__ __launch_bounds__(256) void prep_xt(const float* __restrict__ x,
                                               unsigned short* __restrict__ xt) {
    __shared__ unsigned short t[CIN * TPAD];   // 15,360 B
    int b = blockIdx.x, ihp = blockIdx.y;      // ihp in [0,58)
    int tid = threadIdx.x;
    bool border = (ihp == 0) || (ihp == 57);
    if (!border) {
        int ih = ihp - 1;
        const float* xr = x + (size_t)b * CIN * HW * HW + (size_t)ih * HW;
        #pragma unroll
        for (int i7 = 0; i7 < 7; ++i7) {               // 1792 float4 = 7/thread
            int i = i7 * 256 + tid;
            int c = i / 14, w4 = i - c * 14;
            float4 v = *(const float4*)(xr + (size_t)c * (HW * HW) + w4 * 4);
            bf16x4 pk = { (__bf16)v.x, (__bf16)v.y, (__bf16)v.z, (__bf16)v.w };
            *(bf16x4*)&t[c * TPAD + w4 * 4] = pk;      // 8B aligned (120c+8w4)
        }
    }
    __syncthreads();
    for (int j = tid; j < 928; j += 256) {             // 4*4*58 chunks
        int qq = j / 232, rr = j - qq * 232;
        int oct = rr / 58, col = rr - oct * 58;
        union { unsigned short u[8]; uint4 v; } o;
        o.v = make_uint4(0u, 0u, 0u, 0u);
        if (!border && col >= 1 && col <= 56) {
            #pragma unroll
            for (int k = 0; k < 8; ++k)
                o.u[k] = t[(qq * 32 + oct * 8 + k) * TPAD + (col - 1)];
        }
        *(uint4*)&xt[(((size_t)(b * 16 + qq * 4 + oct)) * PLANEC
                      + (size_t)ihp * 58 + col) * 8] = o.v;
    }
}

// Block = (oc, b-group of 16). wmix layout: [b][s=0..35][oc][32] bf16,
// s = q*9 + rs, chunk = channels q*32..q*32+31 of tap rs.
// bmix fused: threads 0..15 compute the 16 bias rows for this (oc, bg).
__global__ __launch_bounds__(256) void prep_wmix(
        const float* __restrict__ rw, const float* __restrict__ wgt,
        const float* __restrict__ bias,
        unsigned short* __restrict__ wmix, float* __restrict__ bmix) {
    __shared__ float wlds[KEXP * KTOT];     // 36.9 KB
    __shared__ float rwl[16 * KEXP];
    int oc  = blockIdx.x;
    int bg  = blockIdx.y;
    int tid = threadIdx.x;

    if (tid < 16 * KEXP) rwl[tid] = rw[bg * 16 * KEXP + tid];
    const float* wsrc = wgt + (size_t)oc * KTOT;
    #pragma unroll
    for (int e = 0; e < KEXP; ++e) {
        const float* we = wsrc + (size_t)e * OCH * KTOT;
        for (int j = tid; j < KTOT; j += 256) wlds[e * KTOT + j] = we[j];
    }
    __syncthreads();

    if (tid < 16) {                          // fused bmix
        float a = 0.f;
        #pragma unroll
        for (int e = 0; e < KEXP; ++e) a += rwl[tid * KEXP + e] * bias[e * OCH + oc];
        bmix[(size_t)(bg * 16 + tid) * OCH + oc] = a;
    }

    for (int t = tid; t < KTOT; t += 256) {
        int c = t & 127, rs = t >> 7;
        int q = c >> 5, cl = c & 31;
        size_t oidx = ((size_t)(q * 9 + rs) * OCH + oc) * 32 + cl;
        float w8[KEXP];
        #pragma unroll
        for (int e = 0; e < KEXP; ++e) w8[e] = wlds[e * KTOT + c * 9 + rs];
        #pragma unroll
        for (int b = 0; b < 16; ++b) {
            float a = 0.f;
            #pragma unroll
            for (int e = 0; e < KEXP; ++e) a += rwl[b * KEXP + e] * w8[e];
            wmix[(size_t)(bg * 16 + b) * WMIX_PS + oidx] = (unsigned short)f2bf(a);
        }
    }
}

// Block = (sample b = blk&63, 2-row tile), 128 threads = 2 waves.
// Wave w owns oc [w*64, w*64+64) (4 m-subtiles), full N=112. acc[4][7].
// B-dup across waves = 2 (was 4) -> LDS ds_read_b128 count halved; A-dup = 1.
// LDS slab per quarter: [oct(4 x 256 chunks)][row(4)*58+col]; B-read lane
// (quad,ln) hits chunk quad*256 + row*58 + col -> 16 consecutive lanes read
// CONTIGUOUS chunks => zero bank conflicts (proven by R6's layout).
// Double-buffered (2 x 16,384 B -> 5 blocks/CU); stage(q+1) at top of
// compute(q) so the vmcnt drain at the end-of-quarter barrier is free.
// Note: blocks of one sample are stride-64 in blockIdx => same XCD => wmix
// L2-local across its 28 tiles without explicit swizzle.
__global__ __launch_bounds__(128, 2) void condconv_mfma(
        const unsigned short* __restrict__ xt, const unsigned short* __restrict__ wmix,
        const float* __restrict__ bmix, float* __restrict__ out) {
    __shared__ unsigned short patch[2][8192];   // 2 x 16,384 B

    int blk  = blockIdx.x;
    int b    = blk & 63;
    int tile = blk >> 6;               // 0..27
    int oh0  = tile * 2;
    int tid  = threadIdx.x;
    int wave = tid >> 6, lane = tid & 63, ln = lane & 15, quad = lane >> 4;

    // A: wmix[b][s][oc][32]; per-lane base (oc = wave*64 + mt*16 + ln, k-oct = quad)
    const unsigned short* ap = wmix + (size_t)b * WMIX_PS
                             + (size_t)(wave * 64 + ln) * 32 + quad * 8;

    const unsigned short* xb = xt + (size_t)(b * 16) * (PLANEC * 8)
                             + (size_t)oh0 * 58 * 8;

    // staging: wave w covers octets 2w, 2w+1; 8 gl16 of 64 chunks each
    int rcl[8], octl[8];
    #pragma unroll
    for (int i = 0; i < 8; ++i) {
        int rc = (i & 3) * 64 + lane;
        rcl[i]  = (rc > 231) ? 231 : rc;         // clamp into valid 232-chunk slab
        octl[i] = 2 * wave + (i >> 2);
    }

    // B bases + output offsets: n = nt*16 + ln  (N=112 exact, no masking)
    int cb[7], offn[7];
    #pragma unroll
    for (int nt = 0; nt < 7; ++nt) {
        int n   = nt * 16 + ln;
        int row = (n >= 56) ? 1 : 0;
        int ow  = n - row * 56;
        cb[nt]   = (quad * 256 + row * 58 + ow) * 8;   // ushort index
        offn[nt] = (oh0 + row) * HW + ow;
    }

    f32x4 acc[4][7] = {};

    auto stage = [&](int qq, int bf) {
        #pragma unroll
        for (int i = 0; i < 8; ++i) {
            const unsigned short* src = xb
                + ((size_t)(qq * 4 + octl[i]) * PLANEC + rcl[i]) * 8;
            gl16(src, &patch[bf][wave * 4096 + i * 512]);
        }
    };

    stage(0, 0);
    bf16x8 pa[2][4];
    #pragma unroll
    for (int mt = 0; mt < 4; ++mt) {
        pa[0][mt] = *(const bf16x8*)(ap + mt * 512);
        pa[1][mt] = *(const bf16x8*)(ap + 4096 + mt * 512);
    }
    __syncthreads();

    #pragma unroll
    for (int qq = 0; qq < 4; ++qq) {
        if (qq < 3) stage(qq + 1, (qq + 1) & 1);
        #pragma unroll
        for (int s9 = 0; s9 < 9; ++s9) {
            const int s = qq * 9 + s9;
            bf16x8 ca[4];
            #pragma unroll
            for (int mt = 0; mt < 4; ++mt) ca[mt] = pa[s & 1][mt];
            const int sp = (s + 2 < NSTEP) ? (s + 2) : (NSTEP - 1);
            #pragma unroll
            for (int mt = 0; mt < 4; ++mt)
                pa[s & 1][mt] = *(const bf16x8*)(ap + (size_t)sp * 4096 + mt * 512);
            const int r = s9 / 3, sc = s9 - r * 3;
            const int pshift = (r * 58 + sc) * 8;
            #pragma unroll
            for (int nt = 0; nt < 7; ++nt) {
                bf16x8 bb = *(const bf16x8*)&patch[qq & 1][cb[nt] + pshift];
                acc[0][nt] = __builtin_amdgcn_mfma_f32_16x16x32_bf16(ca[0], bb, acc[0][nt], 0, 0, 0);
                acc[1][nt] = __builtin_amdgcn_mfma_f32_16x16x32_bf16(ca[1], bb, acc[1][nt], 0, 0, 0);
                acc[2][nt] = __builtin_amdgcn_mfma_f32_16x16x32_bf16(ca[2], bb, acc[2][nt], 0, 0, 0);
                acc[3][nt] = __builtin_amdgcn_mfma_f32_16x16x32_bf16(ca[3], bb, acc[3][nt], 0, 0, 0);
            }
        }
        __syncthreads();
    }

    // epilogue: D layout col(lane&15)=pixel, row(quad*4+reg)=oc
    const float* bmb = bmix + b * OCH;
    float* ob = out + (size_t)b * OCH * HW * HW;
    #pragma unroll
    for (int mt = 0; mt < 4; ++mt) {
        #pragma unroll
        for (int rg = 0; rg < 4; ++rg) {
            int oc = wave * 64 + mt * 16 + quad * 4 + rg;
            float bv = bmb[oc];
            #pragma unroll
            for (int nt = 0; nt < 7; ++nt)
                ob[(size_t)oc * (HW * HW) + offn[nt]] = acc[mt][nt][rg] + bv;
        }
    }
}

extern "C" void kernel_launch(void* const* d_in, const int* in_sizes, int n_in,
                              void* d_out, int out_size, void* d_ws, size_t ws_size,
                              hipStream_t stream) {
    (void)in_sizes; (void)n_in; (void)out_size; (void)ws_size;
    const float* x    = (const float*)d_in[0];
    const float* rw   = (const float*)d_in[1];
    const float* wgt  = (const float*)d_in[2];
    const float* bias = (const float*)d_in[3];
    float* outp = (float*)d_out;

    // ws layout: wmix (18,874,368 B) | bmix (32 KB) | x_t (55,115,776 B)
    unsigned short* wmix = (unsigned short*)d_ws;
    float* bmix = (float*)((char*)d_ws + (size_t)BS * WMIX_PS * 2);
    unsigned short* xtw = (unsigned short*)((char*)d_ws + (size_t)BS * WMIX_PS * 2 + 32768);

    hipLaunchKernelGGL(prep_xt,   dim3(BS, 58), dim3(256), 0, stream, x, xtw);
    hipLaunchKernelGGL(prep_wmix, dim3(OCH, 4), dim3(256), 0, stream, rw, wgt, bias, wmix, bmix);
    hipLaunchKernelGGL(condconv_mfma, dim3(BS * 28), dim3(128), 0, stream,
                       xtw, wmix, bmix, outp);
}